// Round 5
// baseline (630.088 us; speedup 1.0000x reference)
//
#include <hip/hip_runtime.h>
#include <cstdint>
#include <math.h>

#define F_IN 512
#define HID  16
#define NCLS 40
#define OUT_STRIDE 20
#define TB   128   // nodes per dst-bucket (bucket = dst >> 7)
#define NBA  256   // partition-phase blocks

// ---------- A1: per-block bucket histogram (nt-loads keep L2 clean) ----------
__global__ __launch_bounds__(256) void k_a1(const int* __restrict__ dst,
                                            int* __restrict__ cnt,
                                            int E, int NB, int chunk) {
    __shared__ int h[1024];
    int t = threadIdx.x;
    for (int b = t; b < NB; b += 256) h[b] = 0;
    __syncthreads();
    int e0 = blockIdx.x * chunk, e1 = min(E, e0 + chunk);
    for (int e = e0 + t; e < e1; e += 256) {
        int d = __builtin_nontemporal_load(&dst[e]);
        atomicAdd(&h[d >> 7], 1);
    }
    __syncthreads();
    for (int b = t; b < NB; b += 256) cnt[(size_t)blockIdx.x * NB + b] = h[b];
}

// ---------- A2a: per-bucket exclusive scan across blocks ----------
__global__ __launch_bounds__(NBA) void k_a2a(const int* __restrict__ cnt,
                                             int* __restrict__ offsT,
                                             int* __restrict__ total, int NB) {
    __shared__ int s[NBA];
    int t = threadIdx.x, b = blockIdx.x;
    int v = cnt[(size_t)t * NB + b];
    s[t] = v;
    __syncthreads();
    for (int off = 1; off < NBA; off <<= 1) {
        int tmp = (t >= off) ? s[t - off] : 0;
        __syncthreads();
        s[t] += tmp;
        __syncthreads();
    }
    offsT[(size_t)b * NBA + t] = s[t] - v;
    if (t == NBA - 1) total[b] = s[t];
}

// ---------- A2b: scan bucket totals -> bucket base (+sentinel) ----------
__global__ void k_a2b(const int* __restrict__ total, int* __restrict__ base, int NB) {
    __shared__ int s[1024];
    int t = threadIdx.x;
    int v = (t < NB) ? total[t] : 0;
    s[t] = v;
    __syncthreads();
    for (int off = 1; off < 1024; off <<= 1) {
        int tmp = (t >= off) ? s[t - off] : 0;
        __syncthreads();
        s[t] += tmp;
        __syncthreads();
    }
    if (t < NB) base[t] = s[t] - v;
    if (t == NB - 1) base[NB] = s[t];
}

// ---------- A3: stable partition scatter; per-block contiguous runs ----------
__global__ __launch_bounds__(256) void k_a3(const int* __restrict__ src,
                                            const int* __restrict__ dst,
                                            const int* __restrict__ offsT,
                                            const int* __restrict__ base,
                                            unsigned* __restrict__ bin,
                                            int E, int NB, int chunk) {
    __shared__ int pos[1024];
    int t = threadIdx.x, blk = blockIdx.x;
    for (int b = t; b < NB; b += 256) pos[b] = base[b] + offsT[(size_t)b * NBA + blk];
    __syncthreads();
    int e0 = blk * chunk, e1 = min(E, e0 + chunk);
    for (int e = e0 + t; e < e1; e += 256) {
        int d = __builtin_nontemporal_load(&dst[e]);
        int s = __builtin_nontemporal_load(&src[e]);
        int p = atomicAdd(&pos[d >> 7], 1);
        bin[p] = ((unsigned)s << 7) | (unsigned)(d & (TB - 1));
    }
}

// ---------- Bdeg: bucket-local degree count -> dinv ----------
__global__ __launch_bounds__(256) void k_bdeg(const unsigned* __restrict__ bin,
                                              const int* __restrict__ base,
                                              float* __restrict__ dinv, int N) {
    __shared__ int c[TB];
    int t = threadIdx.x, b = blockIdx.x;
    if (t < TB) c[t] = 0;
    __syncthreads();
    int j0 = base[b], j1 = base[b + 1];
    for (int j = j0 + t; j < j1; j += 256)
        atomicAdd(&c[__builtin_nontemporal_load(&bin[j]) & (TB - 1)], 1);
    __syncthreads();
    int node = b * TB + t;
    if (t < TB && node < N) dinv[node] = rsqrtf((float)c[t] + 1.0f);  // +1 self loop
}

// ---------- GEMM1: h1s[i][c] = (x[i] . W1[:,c]) * dinv[i] (unchanged) ----------
#define KS  4
#define KCH (F_IN / KS)  // 128
__global__ __launch_bounds__(256) void k_gemm1(const float* __restrict__ x,
                                               const float* __restrict__ W1,
                                               const float* __restrict__ dinv,
                                               float* __restrict__ h1s, int n) {
    __shared__ float wlds[F_IN * HID];      // 32 KB
    __shared__ float red[3 * 64 * HID];     // 12 KB
    int t = threadIdx.x;
    int wid = t >> 6;
    int lane = t & 63;

    for (int i = t * 4; i < F_IN * HID; i += 256 * 4)
        *(float4*)&wlds[i] = *(const float4*)&W1[i];
    __syncthreads();

    int row = blockIdx.x * 64 + lane;
    int rclamp = (row < n) ? row : (n - 1);
    const float* xp = x + (size_t)rclamp * F_IN + wid * KCH;
    const float* wp = &wlds[wid * KCH * HID];

    float acc[HID];
#pragma unroll
    for (int c = 0; c < HID; c++) acc[c] = 0.f;

#pragma unroll 8
    for (int k4 = 0; k4 < KCH / 4; k4++) {
        float4 xv = *(const float4*)&xp[k4 * 4];
#pragma unroll
        for (int kk = 0; kk < 4; kk++) {
            float xs = ((const float*)&xv)[kk];
            const float4* wr = (const float4*)&wp[(k4 * 4 + kk) * HID];
#pragma unroll
            for (int cg = 0; cg < 4; cg++) {
                float4 wv = wr[cg];
                acc[cg * 4 + 0] = fmaf(xs, wv.x, acc[cg * 4 + 0]);
                acc[cg * 4 + 1] = fmaf(xs, wv.y, acc[cg * 4 + 1]);
                acc[cg * 4 + 2] = fmaf(xs, wv.z, acc[cg * 4 + 2]);
                acc[cg * 4 + 3] = fmaf(xs, wv.w, acc[cg * 4 + 3]);
            }
        }
    }

    if (wid > 0) {
        float* r = &red[((wid - 1) * 64 + lane) * HID];
#pragma unroll
        for (int cg = 0; cg < 4; cg++)
            *(float4*)&r[cg * 4] = make_float4(acc[cg * 4], acc[cg * 4 + 1],
                                               acc[cg * 4 + 2], acc[cg * 4 + 3]);
    }
    __syncthreads();
    if (wid == 0 && row < n) {
        float dv = dinv[row];
#pragma unroll
        for (int cg = 0; cg < 4; cg++) {
            float4 p0 = *(float4*)&red[(0 * 64 + lane) * HID + cg * 4];
            float4 p1 = *(float4*)&red[(1 * 64 + lane) * HID + cg * 4];
            float4 p2 = *(float4*)&red[(2 * 64 + lane) * HID + cg * 4];
            float4 o;
            o.x = (acc[cg * 4 + 0] + p0.x + p1.x + p2.x) * dv;
            o.y = (acc[cg * 4 + 1] + p0.y + p1.y + p2.y) * dv;
            o.z = (acc[cg * 4 + 2] + p0.z + p1.z + p2.z) * dv;
            o.w = (acc[cg * 4 + 3] + p0.w + p1.w + p2.w) * dv;
            *(float4*)&h1s[(size_t)row * HID + cg * 4] = o;
        }
    }
}

// ---------- Bagg: bucket aggregation in LDS + bias/relu/scale -> z ----------
__global__ __launch_bounds__(256) void k_bagg(const unsigned* __restrict__ bin,
                                              const int* __restrict__ base,
                                              const float* __restrict__ h1s,
                                              const float* __restrict__ dinv,
                                              const float* __restrict__ b1,
                                              float* __restrict__ z, int N) {
    __shared__ float acc[TB * HID];   // 8 KB
    int t = threadIdx.x, b = blockIdx.x;
    for (int i = t; i < TB * HID; i += 256) acc[i] = 0.f;
    __syncthreads();
    int g = t >> 4, l = t & 15;
    int j0 = base[b], j1 = base[b + 1];
    for (int j = j0 + g; j < j1; j += 16) {
        unsigned v = __builtin_nontemporal_load(&bin[j]);
        int dl = v & (TB - 1);
        int s = v >> 7;
        atomicAdd(&acc[dl * HID + l], h1s[(size_t)s * HID + l]);
    }
    __syncthreads();
    float bl = b1[l];
    for (int r = g; r < TB; r += 16) {
        int node = b * TB + r;
        if (node < N) {
            float dv = dinv[node];
            float pre = dv * (acc[r * HID + l] + h1s[(size_t)node * HID + l]) + bl;
            z[(size_t)node * HID + l] = fmaxf(pre, 0.f) * dv;
        }
    }
}

// ---------- B2: layer-2 aggregation for dst%20==0 only ----------
__global__ __launch_bounds__(256) void k_b2(const unsigned* __restrict__ bin,
                                            const int* __restrict__ base,
                                            const float* __restrict__ z,
                                            float* __restrict__ acc2, int N) {
    __shared__ float a2[TB * HID];
    int t = threadIdx.x, b = blockIdx.x;
    for (int i = t; i < TB * HID; i += 256) a2[i] = 0.f;
    __syncthreads();
    int g = t >> 4, l = t & 15;
    int j0 = base[b], j1 = base[b + 1];
    int node0 = b * TB;
    for (int j = j0 + g; j < j1; j += 16) {
        unsigned v = __builtin_nontemporal_load(&bin[j]);
        int dl = v & (TB - 1);
        if ((node0 + dl) % OUT_STRIDE == 0) {
            int s = v >> 7;
            atomicAdd(&a2[dl * HID + l], z[(size_t)s * HID + l]);
        }
    }
    __syncthreads();
    for (int r = g; r < TB; r += 16) {
        int node = node0 + r;
        if (node < N && node % OUT_STRIDE == 0)
            acc2[(size_t)(node / OUT_STRIDE) * HID + l] = a2[r * HID + l];
    }
}

// ---------- out: matvec @W2 + b2 + log_softmax, wave per out row ----------
__global__ void k_out2(const float* __restrict__ z, const float* __restrict__ acc2,
                       const float* __restrict__ dinv, const float* __restrict__ W2,
                       const float* __restrict__ b2, float* __restrict__ out, int nOut) {
    int lane = threadIdx.x & 63;
    int wv = (blockIdx.x * blockDim.x + threadIdx.x) >> 6;
    if (wv >= nOut) return;
    int node = wv * OUT_STRIDE;
    int c = lane & 15;
    float a = dinv[node] * (acc2[(size_t)wv * HID + c] + z[(size_t)node * HID + c]);

    int jj = lane < NCLS ? lane : 0;
    float v = 0.f;
#pragma unroll
    for (int cc = 0; cc < 16; cc++) {
        float ac = __shfl(a, cc);
        v = fmaf(ac, W2[cc * NCLS + jj], v);
    }
    v += b2[jj];

    float vm = lane < NCLS ? v : -INFINITY;
    for (int off = 1; off < 64; off <<= 1) vm = fmaxf(vm, __shfl_xor(vm, off));
    float ex = lane < NCLS ? expf(v - vm) : 0.f;
    float se = ex;
    for (int off = 1; off < 64; off <<= 1) se += __shfl_xor(se, off);
    float ls = logf(se);
    if (lane < NCLS) out[(size_t)wv * NCLS + lane] = v - vm - ls;
}

// ---------------- host launcher ----------------
extern "C" void kernel_launch(void* const* d_in, const int* in_sizes, int n_in,
                              void* d_out, int out_size, void* d_ws, size_t ws_size,
                              hipStream_t stream) {
    const int E = in_sizes[0] / 2;
    const int N = in_sizes[1] / F_IN;
    const int nOut = (N + OUT_STRIDE - 1) / OUT_STRIDE;
    const int NB = (N + TB - 1) / TB;                 // 782
    const int chunk = (E + NBA - 1) / NBA;

    const int* src = (const int*)d_in[0];
    const int* dst = src + E;
    const float* x  = (const float*)d_in[1];
    const float* W1 = (const float*)d_in[2];
    const float* b1 = (const float*)d_in[3];
    const float* W2 = (const float*)d_in[4];
    const float* b2 = (const float*)d_in[5];
    float* out = (float*)d_out;

    uint8_t* w = (uint8_t*)d_ws;
    size_t off = 0;
    auto carve = [&](size_t bytes) {
        void* p = w + off;
        off += (bytes + 15) & ~(size_t)15;
        return p;
    };
    float*    dinv  = (float*)carve((size_t)N * 4);
    unsigned* bin   = (unsigned*)carve((size_t)E * 4);
    int*      cnt   = (int*)carve((size_t)NBA * NB * 4);
    int*      offsT = (int*)carve((size_t)NB * NBA * 4);
    int*      total = (int*)carve((size_t)NB * 4);
    int*      base  = (int*)carve((size_t)(NB + 1) * 4);
    float*    h1s   = (float*)carve((size_t)N * HID * 4);
    float*    z     = (float*)carve((size_t)N * HID * 4);
    float*    acc2  = (float*)carve((size_t)nOut * HID * 4);
    (void)ws_size; (void)n_in; (void)out_size;

    k_a1 <<<NBA, 256, 0, stream>>>(dst, cnt, E, NB, chunk);
    k_a2a<<<NB, NBA, 0, stream>>>(cnt, offsT, total, NB);
    k_a2b<<<1, 1024, 0, stream>>>(total, base, NB);
    k_a3 <<<NBA, 256, 0, stream>>>(src, dst, offsT, base, bin, E, NB, chunk);
    k_bdeg<<<NB, 256, 0, stream>>>(bin, base, dinv, N);
    k_gemm1<<<(N + 63) / 64, 256, 0, stream>>>(x, W1, dinv, h1s, N);
    k_bagg<<<NB, 256, 0, stream>>>(bin, base, h1s, dinv, b1, z, N);
    k_b2 <<<NB, 256, 0, stream>>>(bin, base, z, acc2, N);
    k_out2<<<(nOut * 64 + 255) / 256, 256, 0, stream>>>(z, acc2, dinv, W2, b2, out, nOut);
}

// Round 6
// 537.727 us; speedup vs baseline: 1.1718x; 1.1718x over previous
//
#include <hip/hip_runtime.h>
#include <cstdint>
#include <math.h>

#define F_IN 512
#define HID  16
#define NCLS 40
#define OUT_STRIDE 20
#define TB   128   // nodes per dst-bucket (bucket = dst >> 7)
#define NBA  256   // partition-phase blocks

// ---------- A1: per-block bucket histogram (nt-loads keep L2 clean) ----------
__global__ __launch_bounds__(256) void k_a1(const int* __restrict__ dst,
                                            int* __restrict__ cnt,
                                            int E, int NB, int chunk) {
    __shared__ int h[1024];
    int t = threadIdx.x;
    for (int b = t; b < NB; b += 256) h[b] = 0;
    __syncthreads();
    int e0 = blockIdx.x * chunk, e1 = min(E, e0 + chunk);
    for (int e = e0 + t; e < e1; e += 256) {
        int d = __builtin_nontemporal_load(&dst[e]);
        atomicAdd(&h[d >> 7], 1);
    }
    __syncthreads();
    for (int b = t; b < NB; b += 256) cnt[(size_t)blockIdx.x * NB + b] = h[b];
}

// ---------- A2a: per-bucket exclusive scan across blocks ----------
__global__ __launch_bounds__(NBA) void k_a2a(const int* __restrict__ cnt,
                                             int* __restrict__ offsT,
                                             int* __restrict__ total, int NB) {
    __shared__ int s[NBA];
    int t = threadIdx.x, b = blockIdx.x;
    int v = cnt[(size_t)t * NB + b];
    s[t] = v;
    __syncthreads();
    for (int off = 1; off < NBA; off <<= 1) {
        int tmp = (t >= off) ? s[t - off] : 0;
        __syncthreads();
        s[t] += tmp;
        __syncthreads();
    }
    offsT[(size_t)b * NBA + t] = s[t] - v;
    if (t == NBA - 1) total[b] = s[t];
}

// ---------- A2b: scan bucket totals -> bucket base (+sentinel) ----------
__global__ void k_a2b(const int* __restrict__ total, int* __restrict__ base, int NB) {
    __shared__ int s[1024];
    int t = threadIdx.x;
    int v = (t < NB) ? total[t] : 0;
    s[t] = v;
    __syncthreads();
    for (int off = 1; off < 1024; off <<= 1) {
        int tmp = (t >= off) ? s[t - off] : 0;
        __syncthreads();
        s[t] += tmp;
        __syncthreads();
    }
    if (t < NB) base[t] = s[t] - v;
    if (t == NB - 1) base[NB] = s[t];
}

// ---------- A3: stable partition scatter; per-block contiguous runs ----------
__global__ __launch_bounds__(256) void k_a3(const int* __restrict__ src,
                                            const int* __restrict__ dst,
                                            const int* __restrict__ offsT,
                                            const int* __restrict__ base,
                                            unsigned* __restrict__ bin,
                                            int E, int NB, int chunk) {
    __shared__ int pos[1024];
    int t = threadIdx.x, blk = blockIdx.x;
    for (int b = t; b < NB; b += 256) pos[b] = base[b] + offsT[(size_t)b * NBA + blk];
    __syncthreads();
    int e0 = blk * chunk, e1 = min(E, e0 + chunk);
    for (int e = e0 + t; e < e1; e += 256) {
        int d = __builtin_nontemporal_load(&dst[e]);
        int s = __builtin_nontemporal_load(&src[e]);
        int p = atomicAdd(&pos[d >> 7], 1);
        bin[p] = ((unsigned)s << 7) | (unsigned)(d & (TB - 1));
    }
}

// ---------- Bdeg: bucket-local degree count -> dinv ----------
__global__ __launch_bounds__(256) void k_bdeg(const unsigned* __restrict__ bin,
                                              const int* __restrict__ base,
                                              float* __restrict__ dinv, int N) {
    __shared__ int c[TB];
    int t = threadIdx.x, b = blockIdx.x;
    if (t < TB) c[t] = 0;
    __syncthreads();
    int j0 = base[b], j1 = base[b + 1];
    for (int j = j0 + t; j < j1; j += 256)
        atomicAdd(&c[__builtin_nontemporal_load(&bin[j]) & (TB - 1)], 1);
    __syncthreads();
    int node = b * TB + t;
    if (t < TB && node < N) dinv[node] = rsqrtf((float)c[t] + 1.0f);  // +1 self loop
}

// ---------- GEMM1: h1s[i][c] = (x[i] . W1[:,c]) * dinv[i] (unchanged) ----------
#define KS  4
#define KCH (F_IN / KS)  // 128
__global__ __launch_bounds__(256) void k_gemm1(const float* __restrict__ x,
                                               const float* __restrict__ W1,
                                               const float* __restrict__ dinv,
                                               float* __restrict__ h1s, int n) {
    __shared__ float wlds[F_IN * HID];      // 32 KB
    __shared__ float red[3 * 64 * HID];     // 12 KB
    int t = threadIdx.x;
    int wid = t >> 6;
    int lane = t & 63;

    for (int i = t * 4; i < F_IN * HID; i += 256 * 4)
        *(float4*)&wlds[i] = *(const float4*)&W1[i];
    __syncthreads();

    int row = blockIdx.x * 64 + lane;
    int rclamp = (row < n) ? row : (n - 1);
    const float* xp = x + (size_t)rclamp * F_IN + wid * KCH;
    const float* wp = &wlds[wid * KCH * HID];

    float acc[HID];
#pragma unroll
    for (int c = 0; c < HID; c++) acc[c] = 0.f;

#pragma unroll 8
    for (int k4 = 0; k4 < KCH / 4; k4++) {
        float4 xv = *(const float4*)&xp[k4 * 4];
#pragma unroll
        for (int kk = 0; kk < 4; kk++) {
            float xs = ((const float*)&xv)[kk];
            const float4* wr = (const float4*)&wp[(k4 * 4 + kk) * HID];
#pragma unroll
            for (int cg = 0; cg < 4; cg++) {
                float4 wv = wr[cg];
                acc[cg * 4 + 0] = fmaf(xs, wv.x, acc[cg * 4 + 0]);
                acc[cg * 4 + 1] = fmaf(xs, wv.y, acc[cg * 4 + 1]);
                acc[cg * 4 + 2] = fmaf(xs, wv.z, acc[cg * 4 + 2]);
                acc[cg * 4 + 3] = fmaf(xs, wv.w, acc[cg * 4 + 3]);
            }
        }
    }

    if (wid > 0) {
        float* r = &red[((wid - 1) * 64 + lane) * HID];
#pragma unroll
        for (int cg = 0; cg < 4; cg++)
            *(float4*)&r[cg * 4] = make_float4(acc[cg * 4], acc[cg * 4 + 1],
                                               acc[cg * 4 + 2], acc[cg * 4 + 3]);
    }
    __syncthreads();
    if (wid == 0 && row < n) {
        float dv = dinv[row];
#pragma unroll
        for (int cg = 0; cg < 4; cg++) {
            float4 p0 = *(float4*)&red[(0 * 64 + lane) * HID + cg * 4];
            float4 p1 = *(float4*)&red[(1 * 64 + lane) * HID + cg * 4];
            float4 p2 = *(float4*)&red[(2 * 64 + lane) * HID + cg * 4];
            float4 o;
            o.x = (acc[cg * 4 + 0] + p0.x + p1.x + p2.x) * dv;
            o.y = (acc[cg * 4 + 1] + p0.y + p1.y + p2.y) * dv;
            o.z = (acc[cg * 4 + 2] + p0.z + p1.z + p2.z) * dv;
            o.w = (acc[cg * 4 + 3] + p0.w + p1.w + p2.w) * dv;
            *(float4*)&h1s[(size_t)row * HID + cg * 4] = o;
        }
    }
}

// ---------- Bagg: bucket aggregation in LDS, 8-edge batches for MLP ----------
__global__ __launch_bounds__(256) void k_bagg(const unsigned* __restrict__ bin,
                                              const int* __restrict__ base,
                                              const float* __restrict__ h1s,
                                              const float* __restrict__ dinv,
                                              const float* __restrict__ b1,
                                              float* __restrict__ z, int N) {
    __shared__ float acc[TB * HID];   // 8 KB
    int t = threadIdx.x, b = blockIdx.x;
    for (int i = t; i < TB * HID; i += 256) acc[i] = 0.f;
    __syncthreads();
    int g = t >> 4, l = t & 15;       // 16 groups x 16 lanes
    int j0 = base[b], j1 = base[b + 1];
    int j = j0 + g;
    // main: 8 edges per group per iteration -> 128 gathers in flight per block
    for (; j + 16 * 7 < j1; j += 16 * 8) {
        unsigned v[8];
        float gv[8];
#pragma unroll
        for (int k = 0; k < 8; k++) v[k] = __builtin_nontemporal_load(&bin[j + 16 * k]);
#pragma unroll
        for (int k = 0; k < 8; k++) gv[k] = h1s[(size_t)(v[k] >> 7) * HID + l];
#pragma unroll
        for (int k = 0; k < 8; k++) atomicAdd(&acc[(v[k] & (TB - 1)) * HID + l], gv[k]);
    }
    for (; j < j1; j += 16) {
        unsigned v = bin[j];
        atomicAdd(&acc[(v & (TB - 1)) * HID + l], h1s[(size_t)(v >> 7) * HID + l]);
    }
    __syncthreads();
    float bl = b1[l];
    for (int r = g; r < TB; r += 16) {
        int node = b * TB + r;
        if (node < N) {
            float dv = dinv[node];
            float pre = dv * (acc[r * HID + l] + h1s[(size_t)node * HID + l]) + bl;
            z[(size_t)node * HID + l] = fmaxf(pre, 0.f) * dv;
        }
    }
}

// ---------- B2: layer-2 aggregation for dst%20==0 only (batched) ----------
__global__ __launch_bounds__(256) void k_b2(const unsigned* __restrict__ bin,
                                            const int* __restrict__ base,
                                            const float* __restrict__ z,
                                            float* __restrict__ acc2, int N) {
    __shared__ float a2[TB * HID];
    int t = threadIdx.x, b = blockIdx.x;
    for (int i = t; i < TB * HID; i += 256) a2[i] = 0.f;
    __syncthreads();
    int g = t >> 4, l = t & 15;
    int j0 = base[b], j1 = base[b + 1];
    int node0 = b * TB;
    int j = j0 + g;
    for (; j + 16 * 7 < j1; j += 16 * 8) {
        unsigned v[8];
        bool pass[8];
        float gv[8];
#pragma unroll
        for (int k = 0; k < 8; k++) v[k] = __builtin_nontemporal_load(&bin[j + 16 * k]);
#pragma unroll
        for (int k = 0; k < 8; k++) pass[k] = ((node0 + (int)(v[k] & (TB - 1))) % OUT_STRIDE == 0);
#pragma unroll
        for (int k = 0; k < 8; k++) gv[k] = pass[k] ? z[(size_t)(v[k] >> 7) * HID + l] : 0.f;
#pragma unroll
        for (int k = 0; k < 8; k++)
            if (pass[k]) atomicAdd(&a2[(v[k] & (TB - 1)) * HID + l], gv[k]);
    }
    for (; j < j1; j += 16) {
        unsigned v = bin[j];
        int dl = v & (TB - 1);
        if ((node0 + dl) % OUT_STRIDE == 0)
            atomicAdd(&a2[dl * HID + l], z[(size_t)(v >> 7) * HID + l]);
    }
    __syncthreads();
    for (int r = g; r < TB; r += 16) {
        int node = node0 + r;
        if (node < N && node % OUT_STRIDE == 0)
            acc2[(size_t)(node / OUT_STRIDE) * HID + l] = a2[r * HID + l];
    }
}

// ---------- out: matvec @W2 + b2 + log_softmax, wave per out row ----------
__global__ void k_out2(const float* __restrict__ z, const float* __restrict__ acc2,
                       const float* __restrict__ dinv, const float* __restrict__ W2,
                       const float* __restrict__ b2, float* __restrict__ out, int nOut) {
    int lane = threadIdx.x & 63;
    int wv = (blockIdx.x * blockDim.x + threadIdx.x) >> 6;
    if (wv >= nOut) return;
    int node = wv * OUT_STRIDE;
    int c = lane & 15;
    float a = dinv[node] * (acc2[(size_t)wv * HID + c] + z[(size_t)node * HID + c]);

    int jj = lane < NCLS ? lane : 0;
    float v = 0.f;
#pragma unroll
    for (int cc = 0; cc < 16; cc++) {
        float ac = __shfl(a, cc);
        v = fmaf(ac, W2[cc * NCLS + jj], v);
    }
    v += b2[jj];

    float vm = lane < NCLS ? v : -INFINITY;
    for (int off = 1; off < 64; off <<= 1) vm = fmaxf(vm, __shfl_xor(vm, off));
    float ex = lane < NCLS ? expf(v - vm) : 0.f;
    float se = ex;
    for (int off = 1; off < 64; off <<= 1) se += __shfl_xor(se, off);
    float ls = logf(se);
    if (lane < NCLS) out[(size_t)wv * NCLS + lane] = v - vm - ls;
}

// ---------------- host launcher ----------------
extern "C" void kernel_launch(void* const* d_in, const int* in_sizes, int n_in,
                              void* d_out, int out_size, void* d_ws, size_t ws_size,
                              hipStream_t stream) {
    const int E = in_sizes[0] / 2;
    const int N = in_sizes[1] / F_IN;
    const int nOut = (N + OUT_STRIDE - 1) / OUT_STRIDE;
    const int NB = (N + TB - 1) / TB;                 // 782
    const int chunk = (E + NBA - 1) / NBA;

    const int* src = (const int*)d_in[0];
    const int* dst = src + E;
    const float* x  = (const float*)d_in[1];
    const float* W1 = (const float*)d_in[2];
    const float* b1 = (const float*)d_in[3];
    const float* W2 = (const float*)d_in[4];
    const float* b2 = (const float*)d_in[5];
    float* out = (float*)d_out;

    uint8_t* w = (uint8_t*)d_ws;
    size_t off = 0;
    auto carve = [&](size_t bytes) {
        void* p = w + off;
        off += (bytes + 15) & ~(size_t)15;
        return p;
    };
    float*    dinv  = (float*)carve((size_t)N * 4);
    unsigned* bin   = (unsigned*)carve((size_t)E * 4);
    int*      cnt   = (int*)carve((size_t)NBA * NB * 4);
    int*      offsT = (int*)carve((size_t)NB * NBA * 4);
    int*      total = (int*)carve((size_t)NB * 4);
    int*      base  = (int*)carve((size_t)(NB + 1) * 4);
    float*    h1s   = (float*)carve((size_t)N * HID * 4);
    float*    z     = (float*)carve((size_t)N * HID * 4);
    float*    acc2  = (float*)carve((size_t)nOut * HID * 4);
    (void)ws_size; (void)n_in; (void)out_size;

    k_a1 <<<NBA, 256, 0, stream>>>(dst, cnt, E, NB, chunk);
    k_a2a<<<NB, NBA, 0, stream>>>(cnt, offsT, total, NB);
    k_a2b<<<1, 1024, 0, stream>>>(total, base, NB);
    k_a3 <<<NBA, 256, 0, stream>>>(src, dst, offsT, base, bin, E, NB, chunk);
    k_bdeg<<<NB, 256, 0, stream>>>(bin, base, dinv, N);
    k_gemm1<<<(N + 63) / 64, 256, 0, stream>>>(x, W1, dinv, h1s, N);
    k_bagg<<<NB, 256, 0, stream>>>(bin, base, h1s, dinv, b1, z, N);
    k_b2 <<<NB, 256, 0, stream>>>(bin, base, z, acc2, N);
    k_out2<<<(nOut * 64 + 255) / 256, 256, 0, stream>>>(z, acc2, dinv, W2, b2, out, nOut);
}